// Round 1
// baseline (222.225 us; speedup 1.0000x reference)
//
#include <hip/hip_runtime.h>

typedef __attribute__((ext_vector_type(8))) short short8;
typedef __attribute__((ext_vector_type(4))) float f32x4;

__device__ __forceinline__ unsigned short f2bf(float f) {
  unsigned int u = __float_as_uint(f);
  u += 0x7FFFu + ((u >> 16) & 1u);
  return (unsigned short)(u >> 16);
}
__device__ __forceinline__ float bf2f(unsigned short u) {
  return __uint_as_float(((unsigned int)u) << 16);
}

// ---------------- cast x fp32 -> bf16 ----------------
__global__ __launch_bounds__(256) void cast_x_kernel(const float* __restrict__ x,
                                                     unsigned short* __restrict__ xb,
                                                     int n4) {
  int i = blockIdx.x * 256 + threadIdx.x;
  if (i >= n4) return;
  float4 v = ((const float4*)x)[i];
  ushort4 o;
  o.x = f2bf(v.x); o.y = f2bf(v.y); o.z = f2bf(v.z); o.w = f2bf(v.w);
  ((ushort4*)xb)[i] = o;
}

// ---------------- transpose w (768x2304 fp32) -> wt (2304x768 bf16) ----------------
__global__ void transpose_w_kernel(const float* __restrict__ w,
                                   unsigned short* __restrict__ wt) {
  __shared__ float tile[32][33];
  int n0 = blockIdx.x * 32;  // col of w
  int k0 = blockIdx.y * 32;  // row of w
  for (int i = threadIdx.y; i < 32; i += 8)
    tile[i][threadIdx.x] = w[(size_t)(k0 + i) * 2304 + n0 + threadIdx.x];
  __syncthreads();
  for (int i = threadIdx.y; i < 32; i += 8)
    wt[(size_t)(n0 + i) * 768 + k0 + threadIdx.x] = f2bf(tile[threadIdx.x][i]);
}

// ---------------- QKV GEMM: C[m][n] = sum_k X[m][k] W[k][n] + bias[n] ----------------
// X: 16384x768 bf16, Wt: 2304x768 bf16 (W transposed), out scattered into Qb/Kb/Vb
// Qb/Kb/Vb layout: [b*12+h][t][d] bf16   (48 x 4096 x 64)
#define LDS_AS 40  // padded stride (elems) for 32-wide k tiles; 80B rows (16B aligned, 2-way banks)
__global__ __launch_bounds__(256) void qkv_gemm_kernel(
    const unsigned short* __restrict__ xb,
    const unsigned short* __restrict__ wt,
    const float* __restrict__ bias,
    unsigned short* __restrict__ Qb,
    unsigned short* __restrict__ Kb,
    unsigned short* __restrict__ Vb) {
  __shared__ unsigned short lA[128 * LDS_AS];
  __shared__ unsigned short lB[128 * LDS_AS];
  int m0 = blockIdx.y * 128;
  int n0 = blockIdx.x * 128;
  int tid = threadIdx.x;
  int lane = tid & 63, wid = tid >> 6;
  int wr = wid >> 1, wc = wid & 1;  // 2x2 wave grid, each wave 64x64
  int lr = lane & 15, lg = lane >> 4;
  int lk = lg * 8;

  f32x4 acc[4][4] = {};

  for (int k0 = 0; k0 < 768; k0 += 32) {
    __syncthreads();  // previous iteration's LDS reads complete
#pragma unroll
    for (int ci = tid; ci < 512; ci += 256) {
      int r = ci >> 2, co = (ci & 3) * 8;
      *(uint4*)(&lA[r * LDS_AS + co]) =
          *(const uint4*)(xb + (size_t)(m0 + r) * 768 + k0 + co);
      *(uint4*)(&lB[r * LDS_AS + co]) =
          *(const uint4*)(wt + (size_t)(n0 + r) * 768 + k0 + co);
    }
    __syncthreads();
    short8 af[4], bfr[4];
#pragma unroll
    for (int mi = 0; mi < 4; mi++)
      af[mi] = *(const short8*)(&lA[(wr * 64 + mi * 16 + lr) * LDS_AS + lk]);
#pragma unroll
    for (int ni = 0; ni < 4; ni++)
      bfr[ni] = *(const short8*)(&lB[(wc * 64 + ni * 16 + lr) * LDS_AS + lk]);
#pragma unroll
    for (int mi = 0; mi < 4; mi++)
#pragma unroll
      for (int ni = 0; ni < 4; ni++)
        acc[mi][ni] = __builtin_amdgcn_mfma_f32_16x16x32_bf16(af[mi], bfr[ni], acc[mi][ni], 0, 0, 0);
  }

  // epilogue: add bias, scatter to Q/K/V head-major buffers
#pragma unroll
  for (int ni = 0; ni < 4; ni++) {
    int n = n0 + wc * 64 + ni * 16 + lr;
    float bv = bias[n];
    int which = n / 768;       // 0=q 1=k 2=v
    int idx = n - which * 768; // within q/k/v
    int h = idx >> 6, d = idx & 63;
    unsigned short* dst = (which == 0) ? Qb : ((which == 1) ? Kb : Vb);
#pragma unroll
    for (int mi = 0; mi < 4; mi++) {
#pragma unroll
      for (int reg = 0; reg < 4; reg++) {
        int m = m0 + wr * 64 + mi * 16 + lg * 4 + reg;
        int b = m >> 12, t = m & 4095;
        dst[(((size_t)(b * 12 + h)) * 4096 + t) * 64 + d] = f2bf(acc[mi][ni][reg] + bv);
      }
    }
  }
}

// ---------------- RoPE (in place on Qb, Kb; first 32 dims of each head row) ----------------
__global__ __launch_bounds__(256) void rope_kernel(unsigned short* __restrict__ Qb,
                                                   unsigned short* __restrict__ Kb) {
  const int total = 48 * 4096;
  int r = blockIdx.x * 256 + threadIdx.x;
  if (r >= 2 * total) return;
  unsigned short* buf = (r < total) ? Qb : Kb;
  int rr = (r < total) ? r : (r - total);
  int t = rr & 4095;
  unsigned short* p = buf + (size_t)rr * 64;
  uint4 raw[4];
#pragma unroll
  for (int i = 0; i < 4; i++) raw[i] = ((uint4*)p)[i];
  unsigned short* us = (unsigned short*)raw;
  const float L2T = 13.287712379549449f;  // log2(10000)
#pragma unroll
  for (int j = 0; j < 16; j++) {
    float inv = exp2f(-(float)j * (L2T / 16.0f));
    float ang = (float)t * inv;
    float s, c;
    sincosf(ang, &s, &c);
    float a = bf2f(us[2 * j]), b = bf2f(us[2 * j + 1]);
    us[2 * j] = f2bf(a * c - b * s);
    us[2 * j + 1] = f2bf(b * c + a * s);
  }
#pragma unroll
  for (int i = 0; i < 4; i++) ((uint4*)p)[i] = raw[i];
}

// ---------------- sliding-window attention ----------------
// grid: (32 windows, 48 batch-heads); block 256 (4 waves x 32 query rows)
// keys for window wi: positions (wi-1)*128 .. (wi+2)*128-1, invalid masked
#define KV_S 72  // padded LDS stride (elems): 144B rows, 16B aligned
__global__ __launch_bounds__(256) void attn_kernel(
    const unsigned short* __restrict__ Qb,
    const unsigned short* __restrict__ Kb,
    const unsigned short* __restrict__ Vb,
    float* __restrict__ out) {
  __shared__ unsigned short kS[64 * KV_S];
  __shared__ unsigned short vS[64 * KV_S];   // transposed: [d][key]
  __shared__ unsigned short pS[4][32 * KV_S];
  int wi = blockIdx.x;
  int bh = blockIdx.y;
  int b = bh / 12, h = bh - b * 12;
  int tid = threadIdx.x, lane = tid & 63, wid = tid >> 6;
  int lr = lane & 15, lg = lane >> 4;

  // Q fragments straight from global (rows always valid)
  int tbase = wi * 128 + wid * 32;
  const unsigned short* Qrow = Qb + ((size_t)bh * 4096 + tbase) * 64;
  short8 qf[2][2];
#pragma unroll
  for (int mi = 0; mi < 2; mi++)
#pragma unroll
    for (int ks = 0; ks < 2; ks++)
      qf[mi][ks] = *(const short8*)(Qrow + (mi * 16 + lr) * 64 + ks * 32 + lg * 8);

  f32x4 oacc[2][4] = {};
  float mrow[2][4], lsum[2][4];
#pragma unroll
  for (int mi = 0; mi < 2; mi++)
#pragma unroll
    for (int r = 0; r < 4; r++) { mrow[mi][r] = -1e30f; lsum[mi][r] = 0.0f; }

  const unsigned short* Kbase = Kb + (size_t)bh * 4096 * 64;
  const unsigned short* Vbase = Vb + (size_t)bh * 4096 * 64;
  unsigned short* myP = &pS[wid][0];

  for (int c = 0; c < 6; c++) {
    int kp0 = (wi - 1) * 128 + c * 64;
    if (kp0 + 63 < 0 || kp0 >= 4096) continue;  // block-uniform skip

    __syncthreads();  // prior PV reads done before restaging
    // stage K chunk [key][d]
    for (int ci = tid; ci < 512; ci += 256) {
      int kk = ci >> 3, co = (ci & 7) * 8;
      int kp = kp0 + kk;
      uint4 val = make_uint4(0, 0, 0, 0);
      if (kp >= 0 && kp < 4096) val = *(const uint4*)(Kbase + (size_t)kp * 64 + co);
      *(uint4*)(&kS[kk * KV_S + co]) = val;
    }
    // stage V chunk transposed [d][key]
    for (int ci = tid; ci < 1024; ci += 256) {
      int kk = ci >> 4, dc = (ci & 15) * 4;
      int kp = kp0 + kk;
      ushort4 val = make_ushort4(0, 0, 0, 0);
      if (kp >= 0 && kp < 4096) val = *(const ushort4*)(Vbase + (size_t)kp * 64 + dc);
      vS[(dc + 0) * KV_S + kk] = val.x;
      vS[(dc + 1) * KV_S + kk] = val.y;
      vS[(dc + 2) * KV_S + kk] = val.z;
      vS[(dc + 3) * KV_S + kk] = val.w;
    }
    __syncthreads();

    // S = Q K^T  (scaled)
    f32x4 s[2][4] = {};
#pragma unroll
    for (int ks = 0; ks < 2; ks++) {
      short8 kf[4];
#pragma unroll
      for (int ni = 0; ni < 4; ni++)
        kf[ni] = *(const short8*)(&kS[(ni * 16 + lr) * KV_S + ks * 32 + lg * 8]);
#pragma unroll
      for (int mi = 0; mi < 2; mi++)
#pragma unroll
        for (int ni = 0; ni < 4; ni++)
          s[mi][ni] = __builtin_amdgcn_mfma_f32_16x16x32_bf16(qf[mi][ks], kf[ni], s[mi][ni], 0, 0, 0);
    }
#pragma unroll
    for (int mi = 0; mi < 2; mi++)
#pragma unroll
      for (int ni = 0; ni < 4; ni++) {
        int kp = kp0 + ni * 16 + lr;
        bool valid = (kp >= 0 && kp < 4096);
#pragma unroll
        for (int r = 0; r < 4; r++) {
          float v = s[mi][ni][r] * 0.125f;
          s[mi][ni][r] = valid ? v : -1e30f;
        }
      }

    // online softmax update
    float corr[2][4];
#pragma unroll
    for (int mi = 0; mi < 2; mi++)
#pragma unroll
      for (int r = 0; r < 4; r++) {
        float v = fmaxf(fmaxf(s[mi][0][r], s[mi][1][r]), fmaxf(s[mi][2][r], s[mi][3][r]));
#pragma unroll
        for (int off = 1; off < 16; off <<= 1) v = fmaxf(v, __shfl_xor(v, off, 64));
        float mnew = fmaxf(mrow[mi][r], v);
        corr[mi][r] = __expf(mrow[mi][r] - mnew);
        mrow[mi][r] = mnew;
      }
    float rsum[2][4] = {};
#pragma unroll
    for (int mi = 0; mi < 2; mi++)
#pragma unroll
      for (int ni = 0; ni < 4; ni++)
#pragma unroll
        for (int r = 0; r < 4; r++) {
          float p = __expf(s[mi][ni][r] - mrow[mi][r]);
          s[mi][ni][r] = p;
          rsum[mi][r] += p;
        }
#pragma unroll
    for (int mi = 0; mi < 2; mi++)
#pragma unroll
      for (int r = 0; r < 4; r++) {
        float v = rsum[mi][r];
#pragma unroll
        for (int off = 1; off < 16; off <<= 1) v += __shfl_xor(v, off, 64);
        lsum[mi][r] = lsum[mi][r] * corr[mi][r] + v;
      }
    // write P (bf16) to per-wave LDS; rescale O
#pragma unroll
    for (int mi = 0; mi < 2; mi++)
#pragma unroll
      for (int ni = 0; ni < 4; ni++)
#pragma unroll
        for (int r = 0; r < 4; r++)
          myP[(mi * 16 + lg * 4 + r) * KV_S + ni * 16 + lr] = f2bf(s[mi][ni][r]);
#pragma unroll
    for (int mi = 0; mi < 2; mi++)
#pragma unroll
      for (int di = 0; di < 4; di++)
#pragma unroll
        for (int r = 0; r < 4; r++) oacc[mi][di][r] *= corr[mi][r];
    __syncthreads();

    // O += P V
#pragma unroll
    for (int ks = 0; ks < 2; ks++) {
      short8 pf[2], vf[4];
#pragma unroll
      for (int mi = 0; mi < 2; mi++)
        pf[mi] = *(const short8*)(&myP[(mi * 16 + lr) * KV_S + ks * 32 + lg * 8]);
#pragma unroll
      for (int di = 0; di < 4; di++)
        vf[di] = *(const short8*)(&vS[(di * 16 + lr) * KV_S + ks * 32 + lg * 8]);
#pragma unroll
      for (int mi = 0; mi < 2; mi++)
#pragma unroll
        for (int di = 0; di < 4; di++)
          oacc[mi][di] = __builtin_amdgcn_mfma_f32_16x16x32_bf16(pf[mi], vf[di], oacc[mi][di], 0, 0, 0);
    }
  }

  // epilogue: divide by row sum, write fp32 out[b][t][h*64+d]
#pragma unroll
  for (int mi = 0; mi < 2; mi++)
#pragma unroll
    for (int di = 0; di < 4; di++)
#pragma unroll
      for (int r = 0; r < 4; r++) {
        int trow = tbase + mi * 16 + lg * 4 + r;
        float val = oacc[mi][di][r] / lsum[mi][r];
        out[((size_t)b * 4096 + trow) * 768 + h * 64 + di * 16 + lr] = val;
      }
}

extern "C" void kernel_launch(void* const* d_in, const int* in_sizes, int n_in,
                              void* d_out, int out_size, void* d_ws, size_t ws_size,
                              hipStream_t stream) {
  const float* x = (const float*)d_in[0];      // 4 x 4096 x 768
  const float* w = (const float*)d_in[1];      // 768 x 2304
  const float* bias = (const float*)d_in[2];   // 2304
  float* out = (float*)d_out;                  // 4 x 4096 x 768 fp32

  char* ws = (char*)d_ws;
  unsigned short* xb = (unsigned short*)ws;                       // 16384x768 bf16 (25165824 B)
  unsigned short* wt = (unsigned short*)(ws + 25165824);          // 2304x768 bf16 (3538944 B)
  unsigned short* Qb = (unsigned short*)(ws + 25165824 + 3538944);
  unsigned short* Kb = Qb + 12582912;
  unsigned short* Vb = Kb + 12582912;

  hipLaunchKernelGGL(cast_x_kernel, dim3(12288), dim3(256), 0, stream, x, xb, 3145728);
  hipLaunchKernelGGL(transpose_w_kernel, dim3(72, 24), dim3(32, 8), 0, stream, w, wt);
  hipLaunchKernelGGL(qkv_gemm_kernel, dim3(18, 128), dim3(256), 0, stream, xb, wt, bias, Qb, Kb, Vb);
  hipLaunchKernelGGL(rope_kernel, dim3(1536), dim3(256), 0, stream, Qb, Kb);
  hipLaunchKernelGGL(attn_kernel, dim3(32, 48), dim3(256), 0, stream, Qb, Kb, Vb, out);
}

// Round 4
// 181.811 us; speedup vs baseline: 1.2223x; 1.2223x over previous
//
#include <hip/hip_runtime.h>

typedef __attribute__((ext_vector_type(8))) short short8;
typedef __attribute__((ext_vector_type(16))) float f32x16;
typedef __attribute__((ext_vector_type(4))) float f32x4;

__device__ __forceinline__ unsigned short f2bf(float f) {
  unsigned int u = __float_as_uint(f);
  u += 0x7FFFu + ((u >> 16) & 1u);
  return (unsigned short)(u >> 16);
}
__device__ __forceinline__ float bf2f(unsigned short u) {
  return __uint_as_float(((unsigned int)u) << 16);
}

// ---------------- cast x fp32 -> bf16 ----------------
__global__ __launch_bounds__(256) void cast_x_kernel(const float* __restrict__ x,
                                                     unsigned short* __restrict__ xb,
                                                     int n4) {
  int i = blockIdx.x * 256 + threadIdx.x;
  if (i >= n4) return;
  float4 v = ((const float4*)x)[i];
  ushort4 o;
  o.x = f2bf(v.x); o.y = f2bf(v.y); o.z = f2bf(v.z); o.w = f2bf(v.w);
  ((ushort4*)xb)[i] = o;
}

// ---------------- transpose w (768x2304 fp32) -> wt (2304x768 bf16) ----------------
__global__ void transpose_w_kernel(const float* __restrict__ w,
                                   unsigned short* __restrict__ wt) {
  __shared__ float tile[32][33];
  int n0 = blockIdx.x * 32;  // col of w
  int k0 = blockIdx.y * 32;  // row of w
  for (int i = threadIdx.y; i < 32; i += 8)
    tile[i][threadIdx.x] = w[(size_t)(k0 + i) * 2304 + n0 + threadIdx.x];
  __syncthreads();
  for (int i = threadIdx.y; i < 32; i += 8)
    wt[(size_t)(n0 + i) * 768 + k0 + threadIdx.x] = f2bf(tile[threadIdx.x][i]);
}

// ---------------- QKV GEMM (unchanged from passing R1) ----------------
#define LDS_AS 40
__global__ __launch_bounds__(256) void qkv_gemm_kernel(
    const unsigned short* __restrict__ xb,
    const unsigned short* __restrict__ wt,
    const float* __restrict__ bias,
    unsigned short* __restrict__ Qb,
    unsigned short* __restrict__ Kb,
    unsigned short* __restrict__ Vb) {
  __shared__ unsigned short lA[128 * LDS_AS];
  __shared__ unsigned short lB[128 * LDS_AS];
  int m0 = blockIdx.y * 128;
  int n0 = blockIdx.x * 128;
  int tid = threadIdx.x;
  int lane = tid & 63, wid = tid >> 6;
  int wr = wid >> 1, wc = wid & 1;
  int lr = lane & 15, lg = lane >> 4;
  int lk = lg * 8;

  f32x4 acc[4][4] = {};

  for (int k0 = 0; k0 < 768; k0 += 32) {
    __syncthreads();
#pragma unroll
    for (int ci = tid; ci < 512; ci += 256) {
      int r = ci >> 2, co = (ci & 3) * 8;
      *(uint4*)(&lA[r * LDS_AS + co]) =
          *(const uint4*)(xb + (size_t)(m0 + r) * 768 + k0 + co);
      *(uint4*)(&lB[r * LDS_AS + co]) =
          *(const uint4*)(wt + (size_t)(n0 + r) * 768 + k0 + co);
    }
    __syncthreads();
    short8 af[4], bfr[4];
#pragma unroll
    for (int mi = 0; mi < 4; mi++)
      af[mi] = *(const short8*)(&lA[(wr * 64 + mi * 16 + lr) * LDS_AS + lk]);
#pragma unroll
    for (int ni = 0; ni < 4; ni++)
      bfr[ni] = *(const short8*)(&lB[(wc * 64 + ni * 16 + lr) * LDS_AS + lk]);
#pragma unroll
    for (int mi = 0; mi < 4; mi++)
#pragma unroll
      for (int ni = 0; ni < 4; ni++)
        acc[mi][ni] = __builtin_amdgcn_mfma_f32_16x16x32_bf16(af[mi], bfr[ni], acc[mi][ni], 0, 0, 0);
  }

#pragma unroll
  for (int ni = 0; ni < 4; ni++) {
    int n = n0 + wc * 64 + ni * 16 + lr;
    float bv = bias[n];
    int which = n / 768;
    int idx = n - which * 768;
    int h = idx >> 6, d = idx & 63;
    unsigned short* dst = (which == 0) ? Qb : ((which == 1) ? Kb : Vb);
#pragma unroll
    for (int mi = 0; mi < 4; mi++) {
#pragma unroll
      for (int reg = 0; reg < 4; reg++) {
        int m = m0 + wr * 64 + mi * 16 + lg * 4 + reg;
        int b = m >> 12, t = m & 4095;
        dst[(((size_t)(b * 12 + h)) * 4096 + t) * 64 + d] = f2bf(acc[mi][ni][reg] + bv);
      }
    }
  }
}

// ---------------- RoPE (in place; Q also pre-scaled by 1/8 across ALL 64 dims) ----------------
__global__ __launch_bounds__(256) void rope_kernel(unsigned short* __restrict__ Qb,
                                                   unsigned short* __restrict__ Kb) {
  const int total = 48 * 4096;
  int r = blockIdx.x * 256 + threadIdx.x;
  if (r >= 2 * total) return;
  bool isQ = (r < total);
  unsigned short* buf = isQ ? Qb : Kb;
  int rr = isQ ? r : (r - total);
  int t = rr & 4095;
  float sc = isQ ? 0.125f : 1.0f;
  unsigned short* p = buf + (size_t)rr * 64;
  uint4 raw[8];  // full 64 bf16 = 128 bytes
#pragma unroll
  for (int i = 0; i < 8; i++) raw[i] = ((uint4*)p)[i];
  unsigned short* us = (unsigned short*)raw;
  const float L2T = 13.287712379549449f;  // log2(10000)
#pragma unroll
  for (int j = 0; j < 16; j++) {
    float inv = exp2f(-(float)j * (L2T / 16.0f));
    float ang = (float)t * inv;
    float s, c;
    sincosf(ang, &s, &c);
    float a = bf2f(us[2 * j]), b = bf2f(us[2 * j + 1]);
    us[2 * j] = f2bf((a * c - b * s) * sc);
    us[2 * j + 1] = f2bf((b * c + a * s) * sc);
  }
  if (isQ) {
#pragma unroll
    for (int j = 32; j < 64; j++) us[j] = f2bf(bf2f(us[j]) * sc);
  }
#pragma unroll
  for (int i = 0; i < 8; i++) ((uint4*)p)[i] = raw[i];
}

// ---------------- sliding-window attention, 32x32 MFMA (m214 recipe) ----------------
// grid: (32 windows, 48 batch-heads); block 256 = 4 waves x 32 query rows.
// Chunk = 64 keys; all surviving chunks fully in-range -> no masking needed.
// S^T = mfma(K,Q): C layout col=lane&31=q, row=(r&3)+8*(r>>2)+4*hi=key  [m74/m101]
// P repack: 4x v_cvt_pk_bf16_f32 + 2x v_permlane32_swap per 16-key step [m214 v22]
// O^T = mfma(V^T, P^T): q stays lane-local -> softmax state never crosses lanes.
#define KV_S 72  // row stride (elems): 144B, 16B-aligned; b128 col-reads are conflict-minimal
__global__ __launch_bounds__(256) void attn_kernel(
    const unsigned short* __restrict__ Qb,
    const unsigned short* __restrict__ Kb,
    const unsigned short* __restrict__ Vb,
    float* __restrict__ out) {
  __shared__ unsigned short kS[64 * KV_S];  // [key][dim]
  __shared__ unsigned short vS[64 * KV_S];  // [dim][key] (transposed)
  int wi = blockIdx.x;
  int bh = blockIdx.y;
  int b = bh / 12, h = bh - b * 12;
  int tid = threadIdx.x, lane = tid & 63, wid = tid >> 6;
  int l31 = lane & 31, hi = lane >> 5;

  // Q fragments: B-operand layout col=lane&31=q, k=hi*8+e. Q pre-scaled by 1/8.
  int qb0 = wi * 128 + wid * 32;
  const unsigned short* Qrow = Qb + ((size_t)bh * 4096 + qb0) * 64;
  short8 qf[4];
#pragma unroll
  for (int kk = 0; kk < 4; kk++)
    qf[kk] = *(const short8*)(Qrow + (size_t)l31 * 64 + kk * 16 + hi * 8);

  f32x16 oacc[2];
#pragma unroll
  for (int dt = 0; dt < 2; dt++)
#pragma unroll
    for (int r = 0; r < 16; r++) oacc[dt][r] = 0.0f;
  float mrow = -1e30f, lsum = 0.0f;

  const unsigned short* Kbase = Kb + (size_t)bh * 4096 * 64;
  const unsigned short* Vbase = Vb + (size_t)bh * 4096 * 64;

  int vk = tid & 63;  // V staging: this thread's key
  int vq = tid >> 6;  // and d-quarter

  for (int c = 0; c < 6; c++) {
    int kp0 = (wi - 1) * 128 + c * 64;
    if (kp0 < 0 || kp0 >= 4096) continue;  // block-uniform; surviving chunks fully valid

    __syncthreads();  // prior chunk's LDS reads complete
    // stage K [key][dim], 16B coalesced
#pragma unroll
    for (int ci = tid; ci < 512; ci += 256) {
      int kk = ci >> 3, co = (ci & 7) * 8;
      *(uint4*)(&kS[kk * KV_S + co]) = *(const uint4*)(Kbase + (size_t)(kp0 + kk) * 64 + co);
    }
    // stage V transposed [dim][key]
    {
      const unsigned short* vp = Vbase + (size_t)(kp0 + vk) * 64 + vq * 16;
      uint4 v0 = *(const uint4*)(vp);
      uint4 v1 = *(const uint4*)(vp + 8);
      const unsigned short* e = (const unsigned short*)&v0;
#pragma unroll
      for (int i = 0; i < 8; i++) vS[(vq * 16 + i) * KV_S + vk] = e[i];
      e = (const unsigned short*)&v1;
#pragma unroll
      for (int i = 0; i < 8; i++) vS[(vq * 16 + 8 + i) * KV_S + vk] = e[i];
    }
    __syncthreads();

    // S^T tiles (2 x 32 keys): s[kt] = K_tile · Q^T
    f32x16 s[2];
#pragma unroll
    for (int kt = 0; kt < 2; kt++) {
      f32x16 acc;
#pragma unroll
      for (int r = 0; r < 16; r++) acc[r] = 0.0f;
#pragma unroll
      for (int kk = 0; kk < 4; kk++) {
        short8 kf = *(const short8*)(&kS[(kt * 32 + l31) * KV_S + kk * 16 + hi * 8]);
        acc = __builtin_amdgcn_mfma_f32_32x32x16_bf16(kf, qf[kk], acc, 0, 0, 0);
      }
      s[kt] = acc;
    }

    // online softmax: lane owns q=l31; halves hold complementary keys -> 1 shfl each
    float vmax = -1e30f;
#pragma unroll
    for (int kt = 0; kt < 2; kt++)
#pragma unroll
      for (int r = 0; r < 16; r++) vmax = fmaxf(vmax, s[kt][r]);
    vmax = fmaxf(vmax, __shfl_xor(vmax, 32, 64));
    float mnew = fmaxf(mrow, vmax);
    float corr = __expf(mrow - mnew);
    mrow = mnew;
    float rs = 0.0f;
#pragma unroll
    for (int kt = 0; kt < 2; kt++)
#pragma unroll
      for (int r = 0; r < 16; r++) {
        float p = __expf(s[kt][r] - mnew);
        s[kt][r] = p;
        rs += p;
      }
    rs += __shfl_xor(rs, 32, 64);
    lsum = lsum * corr + rs;
#pragma unroll
    for (int dt = 0; dt < 2; dt++)
#pragma unroll
      for (int r = 0; r < 16; r++) oacc[dt][r] *= corr;

    // P pack (cvt_pk + permlane32_swap) and PV: O^T += V^T · P^T
#pragma unroll
    for (int kt = 0; kt < 2; kt++) {
#pragma unroll
      for (int kk = 0; kk < 2; kk++) {
        unsigned a0, a1, b0, b1;
        asm("v_cvt_pk_bf16_f32 %0, %1, %2" : "=v"(a0) : "v"(s[kt][kk * 8 + 0]), "v"(s[kt][kk * 8 + 1]));
        asm("v_cvt_pk_bf16_f32 %0, %1, %2" : "=v"(a1) : "v"(s[kt][kk * 8 + 2]), "v"(s[kt][kk * 8 + 3]));
        asm("v_cvt_pk_bf16_f32 %0, %1, %2" : "=v"(b0) : "v"(s[kt][kk * 8 + 4]), "v"(s[kt][kk * 8 + 5]));
        asm("v_cvt_pk_bf16_f32 %0, %1, %2" : "=v"(b1) : "v"(s[kt][kk * 8 + 6]), "v"(s[kt][kk * 8 + 7]));
        asm("v_permlane32_swap_b32 %0, %1" : "+v"(a0), "+v"(b0));
        asm("v_permlane32_swap_b32 %0, %1" : "+v"(a1), "+v"(b1));
        union { unsigned u[4]; short8 v; } pb;
        pb.u[0] = a0; pb.u[1] = a1; pb.u[2] = b0; pb.u[3] = b1;
#pragma unroll
        for (int dt = 0; dt < 2; dt++) {
          short8 vf = *(const short8*)(&vS[(dt * 32 + l31) * KV_S + kt * 32 + kk * 16 + hi * 8]);
          oacc[dt] = __builtin_amdgcn_mfma_f32_32x32x16_bf16(vf, pb.v, oacc[dt], 0, 0, 0);
        }
      }
    }
  }

  // epilogue: O^T regs -> d = dt*32 + (r&3) + 8*(r>>2) + 4*hi, q = l31; float4 stores
  float inv = 1.0f / lsum;
  float* orow = out + ((size_t)b * 4096 + qb0 + l31) * 768 + h * 64;
#pragma unroll
  for (int dt = 0; dt < 2; dt++)
#pragma unroll
    for (int g = 0; g < 4; g++) {
      float4 o;
      o.x = oacc[dt][g * 4 + 0] * inv;
      o.y = oacc[dt][g * 4 + 1] * inv;
      o.z = oacc[dt][g * 4 + 2] * inv;
      o.w = oacc[dt][g * 4 + 3] * inv;
      *(float4*)(orow + dt * 32 + g * 8 + hi * 4) = o;
    }
}

extern "C" void kernel_launch(void* const* d_in, const int* in_sizes, int n_in,
                              void* d_out, int out_size, void* d_ws, size_t ws_size,
                              hipStream_t stream) {
  const float* x = (const float*)d_in[0];      // 4 x 4096 x 768
  const float* w = (const float*)d_in[1];      // 768 x 2304
  const float* bias = (const float*)d_in[2];   // 2304
  float* out = (float*)d_out;                  // 4 x 4096 x 768 fp32

  char* ws = (char*)d_ws;
  unsigned short* xb = (unsigned short*)ws;                       // 16384x768 bf16
  unsigned short* wt = (unsigned short*)(ws + 25165824);          // 2304x768 bf16
  unsigned short* Qb = (unsigned short*)(ws + 25165824 + 3538944);
  unsigned short* Kb = Qb + 12582912;
  unsigned short* Vb = Kb + 12582912;

  hipLaunchKernelGGL(cast_x_kernel, dim3(12288), dim3(256), 0, stream, x, xb, 3145728);
  hipLaunchKernelGGL(transpose_w_kernel, dim3(72, 24), dim3(32, 8), 0, stream, w, wt);
  hipLaunchKernelGGL(qkv_gemm_kernel, dim3(18, 128), dim3(256), 0, stream, xb, wt, bias, Qb, Kb, Vb);
  hipLaunchKernelGGL(rope_kernel, dim3(1536), dim3(256), 0, stream, Qb, Kb);
  hipLaunchKernelGGL(attn_kernel, dim3(32, 48), dim3(256), 0, stream, Qb, Kb, Vb, out);
}

// Round 5
// 152.534 us; speedup vs baseline: 1.4569x; 1.1919x over previous
//
#include <hip/hip_runtime.h>

typedef __attribute__((ext_vector_type(8))) short short8;
typedef __attribute__((ext_vector_type(16))) float f32x16;
typedef __attribute__((ext_vector_type(4))) float f32x4;

__device__ __forceinline__ unsigned short f2bf(float f) {
  unsigned int u = __float_as_uint(f);
  u += 0x7FFFu + ((u >> 16) & 1u);
  return (unsigned short)(u >> 16);
}
__device__ __forceinline__ float bf2f(unsigned short u) {
  return __uint_as_float(((unsigned int)u) << 16);
}

// async global->LDS, 16B per lane; LDS dest = wave-uniform base + lane*16
__device__ __forceinline__ void gload16(const unsigned short* g, unsigned short* l) {
  __builtin_amdgcn_global_load_lds(
      (const __attribute__((address_space(1))) void*)g,
      (__attribute__((address_space(3))) void*)l, 16, 0, 0);
}

// ---------------- cast x fp32 -> bf16 ----------------
__global__ __launch_bounds__(256) void cast_x_kernel(const float* __restrict__ x,
                                                     unsigned short* __restrict__ xb,
                                                     int n4) {
  int i = blockIdx.x * 256 + threadIdx.x;
  if (i >= n4) return;
  float4 v = ((const float4*)x)[i];
  ushort4 o;
  o.x = f2bf(v.x); o.y = f2bf(v.y); o.z = f2bf(v.z); o.w = f2bf(v.w);
  ((ushort4*)xb)[i] = o;
}

// ---------------- transpose w (768x2304 fp32) -> wt (2304x768 bf16) ----------------
__global__ void transpose_w_kernel(const float* __restrict__ w,
                                   unsigned short* __restrict__ wt) {
  __shared__ float tile[32][33];
  int n0 = blockIdx.x * 32;  // col of w
  int k0 = blockIdx.y * 32;  // row of w
  for (int i = threadIdx.y; i < 32; i += 8)
    tile[i][threadIdx.x] = w[(size_t)(k0 + i) * 2304 + n0 + threadIdx.x];
  __syncthreads();
  for (int i = threadIdx.y; i < 32; i += 8)
    wt[(size_t)(n0 + i) * 768 + k0 + threadIdx.x] = f2bf(tile[threadIdx.x][i]);
}

// ---------------- QKV GEMM: global_load_lds(16B) + BK=64 + XOR-swizzled LDS ----------------
// LDS tile [128 rows][64 cols] bf16, linear 128B rows; granule (16B) g of row r
// stored at slot g^(r&7)  [G4 swizzle]. Source global addr pre-applies the inverse
// (same XOR) so gload_lds's linear lane->LDS mapping lands data swizzled (rule #21).
__global__ __launch_bounds__(256) void qkv_gemm_kernel(
    const unsigned short* __restrict__ xb,
    const unsigned short* __restrict__ wt,
    const float* __restrict__ bias,
    unsigned short* __restrict__ Qb,
    unsigned short* __restrict__ Kb,
    unsigned short* __restrict__ Vb) {
  __shared__ unsigned short lA[128 * 64];
  __shared__ unsigned short lB[128 * 64];
  // XCD swizzle: 2304 blocks, 2304%8==0 -> bijective chunked remap (T1)
  int bid = blockIdx.x;
  int swz = (bid & 7) * 288 + (bid >> 3);
  int mt = swz / 18, nt = swz - mt * 18;
  int m0 = mt * 128, n0 = nt * 128;

  int tid = threadIdx.x;
  int lane = tid & 63, wid = tid >> 6;
  int wr = wid >> 1, wc = wid & 1;
  int lr = lane & 15, lg = lane >> 4;
  int lswz = lr & 7;

  // per-thread staging source offsets (swizzle pre-applied to global col)
  int offA[4], offB[4];
  unsigned short* ldsA[4];
  unsigned short* ldsB[4];
#pragma unroll
  for (int i = 0; i < 4; i++) {
    int gi = (wid * 4 + i) * 64 + lane;  // granule id in tile
    int r = gi >> 3;                     // row 0..127
    int gcl = (gi & 7) ^ (r & 7);        // logical col-granule this lane must fetch
    offA[i] = (m0 + r) * 768 + gcl * 8;
    offB[i] = (n0 + r) * 768 + gcl * 8;
    ldsA[i] = &lA[(wid * 4 + i) * 512];  // wave-uniform (wid uniform)
    ldsB[i] = &lB[(wid * 4 + i) * 512];
  }

  f32x4 acc[4][4] = {};
  const int rowA = (wr * 64 + lr) * 64;
  const int rowB = (wc * 64 + lr) * 64;

  for (int k0 = 0; k0 < 768; k0 += 64) {
    __syncthreads();  // all reads of previous tile complete
#pragma unroll
    for (int i = 0; i < 4; i++) gload16(xb + offA[i] + k0, ldsA[i]);
#pragma unroll
    for (int i = 0; i < 4; i++) gload16(wt + offB[i] + k0, ldsB[i]);
    __syncthreads();  // vmcnt drained by compiler before barrier

    short8 af[4][2], bfr[4][2];
#pragma unroll
    for (int ks = 0; ks < 2; ks++) {
      int c = ((ks * 4 + lg) ^ lswz) * 8;
#pragma unroll
      for (int mi = 0; mi < 4; mi++)
        af[mi][ks] = *(const short8*)(&lA[rowA + mi * 1024 + c]);
#pragma unroll
      for (int ni = 0; ni < 4; ni++)
        bfr[ni][ks] = *(const short8*)(&lB[rowB + ni * 1024 + c]);
    }
#pragma unroll
    for (int ks = 0; ks < 2; ks++)
#pragma unroll
      for (int mi = 0; mi < 4; mi++)
#pragma unroll
        for (int ni = 0; ni < 4; ni++)
          acc[mi][ni] = __builtin_amdgcn_mfma_f32_16x16x32_bf16(af[mi][ks], bfr[ni][ks], acc[mi][ni], 0, 0, 0);
  }

  // epilogue: add bias, fold 1/8 scale into Q, scatter to head-major buffers
#pragma unroll
  for (int ni = 0; ni < 4; ni++) {
    int n = n0 + wc * 64 + ni * 16 + lr;
    float bv = bias[n];
    int which = n / 768;
    int idx = n - which * 768;
    int h = idx >> 6, d = idx & 63;
    float scl = (which == 0) ? 0.125f : 1.0f;
    unsigned short* dst = (which == 0) ? Qb : ((which == 1) ? Kb : Vb);
#pragma unroll
    for (int mi = 0; mi < 4; mi++) {
#pragma unroll
      for (int reg = 0; reg < 4; reg++) {
        int m = m0 + wr * 64 + mi * 16 + lg * 4 + reg;
        int b = m >> 12, t = m & 4095;
        dst[(((size_t)(b * 12 + h)) * 4096 + t) * 64 + d] = f2bf((acc[mi][ni][reg] + bv) * scl);
      }
    }
  }
}

// ---------------- RoPE (rotate first 32 dims in place; scale already folded into GEMM) ----
__global__ __launch_bounds__(256) void rope_kernel(unsigned short* __restrict__ Qb,
                                                   unsigned short* __restrict__ Kb) {
  const int total = 48 * 4096;
  int r = blockIdx.x * 256 + threadIdx.x;
  if (r >= 2 * total) return;
  bool isQ = (r < total);
  unsigned short* buf = isQ ? Qb : Kb;
  int rr = isQ ? r : (r - total);
  int t = rr & 4095;
  unsigned short* p = buf + (size_t)rr * 64;
  uint4 raw[4];  // dims 0..31 only (64B)
#pragma unroll
  for (int i = 0; i < 4; i++) raw[i] = ((uint4*)p)[i];
  unsigned short* us = (unsigned short*)raw;
  const float L2T = 13.287712379549449f;  // log2(10000)
#pragma unroll
  for (int j = 0; j < 16; j++) {
    float inv = exp2f(-(float)j * (L2T / 16.0f));
    float ang = (float)t * inv;
    float s, c;
    sincosf(ang, &s, &c);
    float a = bf2f(us[2 * j]), b = bf2f(us[2 * j + 1]);
    us[2 * j] = f2bf(a * c - b * s);
    us[2 * j + 1] = f2bf(b * c + a * s);
  }
#pragma unroll
  for (int i = 0; i < 4; i++) ((uint4*)p)[i] = raw[i];
}

// ---------------- sliding-window attention, 32x32 MFMA (unchanged, passing) ----------------
#define KV_S 72
__global__ __launch_bounds__(256) void attn_kernel(
    const unsigned short* __restrict__ Qb,
    const unsigned short* __restrict__ Kb,
    const unsigned short* __restrict__ Vb,
    float* __restrict__ out) {
  __shared__ unsigned short kS[64 * KV_S];  // [key][dim]
  __shared__ unsigned short vS[64 * KV_S];  // [dim][key]
  int wi = blockIdx.x;
  int bh = blockIdx.y;
  int b = bh / 12, h = bh - b * 12;
  int tid = threadIdx.x, lane = tid & 63, wid = tid >> 6;
  int l31 = lane & 31, hi = lane >> 5;

  int qb0 = wi * 128 + wid * 32;
  const unsigned short* Qrow = Qb + ((size_t)bh * 4096 + qb0) * 64;
  short8 qf[4];
#pragma unroll
  for (int kk = 0; kk < 4; kk++)
    qf[kk] = *(const short8*)(Qrow + (size_t)l31 * 64 + kk * 16 + hi * 8);

  f32x16 oacc[2];
#pragma unroll
  for (int dt = 0; dt < 2; dt++)
#pragma unroll
    for (int r = 0; r < 16; r++) oacc[dt][r] = 0.0f;
  float mrow = -1e30f, lsum = 0.0f;

  const unsigned short* Kbase = Kb + (size_t)bh * 4096 * 64;
  const unsigned short* Vbase = Vb + (size_t)bh * 4096 * 64;

  int vk = tid & 63;
  int vq = tid >> 6;

  for (int c = 0; c < 6; c++) {
    int kp0 = (wi - 1) * 128 + c * 64;
    if (kp0 < 0 || kp0 >= 4096) continue;

    __syncthreads();
#pragma unroll
    for (int ci = tid; ci < 512; ci += 256) {
      int kk = ci >> 3, co = (ci & 7) * 8;
      *(uint4*)(&kS[kk * KV_S + co]) = *(const uint4*)(Kbase + (size_t)(kp0 + kk) * 64 + co);
    }
    {
      const unsigned short* vp = Vbase + (size_t)(kp0 + vk) * 64 + vq * 16;
      uint4 v0 = *(const uint4*)(vp);
      uint4 v1 = *(const uint4*)(vp + 8);
      const unsigned short* e = (const unsigned short*)&v0;
#pragma unroll
      for (int i = 0; i < 8; i++) vS[(vq * 16 + i) * KV_S + vk] = e[i];
      e = (const unsigned short*)&v1;
#pragma unroll
      for (int i = 0; i < 8; i++) vS[(vq * 16 + 8 + i) * KV_S + vk] = e[i];
    }
    __syncthreads();

    f32x16 s[2];
#pragma unroll
    for (int kt = 0; kt < 2; kt++) {
      f32x16 acc;
#pragma unroll
      for (int r = 0; r < 16; r++) acc[r] = 0.0f;
#pragma unroll
      for (int kk = 0; kk < 4; kk++) {
        short8 kf = *(const short8*)(&kS[(kt * 32 + l31) * KV_S + kk * 16 + hi * 8]);
        acc = __builtin_amdgcn_mfma_f32_32x32x16_bf16(kf, qf[kk], acc, 0, 0, 0);
      }
      s[kt] = acc;
    }

    float vmax = -1e30f;
#pragma unroll
    for (int kt = 0; kt < 2; kt++)
#pragma unroll
      for (int r = 0; r < 16; r++) vmax = fmaxf(vmax, s[kt][r]);
    vmax = fmaxf(vmax, __shfl_xor(vmax, 32, 64));
    float mnew = fmaxf(mrow, vmax);
    float corr = __expf(mrow - mnew);
    mrow = mnew;
    float rs = 0.0f;
#pragma unroll
    for (int kt = 0; kt < 2; kt++)
#pragma unroll
      for (int r = 0; r < 16; r++) {
        float p = __expf(s[kt][r] - mnew);
        s[kt][r] = p;
        rs += p;
      }
    rs += __shfl_xor(rs, 32, 64);
    lsum = lsum * corr + rs;
#pragma unroll
    for (int dt = 0; dt < 2; dt++)
#pragma unroll
      for (int r = 0; r < 16; r++) oacc[dt][r] *= corr;

#pragma unroll
    for (int kt = 0; kt < 2; kt++) {
#pragma unroll
      for (int kk = 0; kk < 2; kk++) {
        unsigned a0, a1, b0, b1;
        asm("v_cvt_pk_bf16_f32 %0, %1, %2" : "=v"(a0) : "v"(s[kt][kk * 8 + 0]), "v"(s[kt][kk * 8 + 1]));
        asm("v_cvt_pk_bf16_f32 %0, %1, %2" : "=v"(a1) : "v"(s[kt][kk * 8 + 2]), "v"(s[kt][kk * 8 + 3]));
        asm("v_cvt_pk_bf16_f32 %0, %1, %2" : "=v"(b0) : "v"(s[kt][kk * 8 + 4]), "v"(s[kt][kk * 8 + 5]));
        asm("v_cvt_pk_bf16_f32 %0, %1, %2" : "=v"(b1) : "v"(s[kt][kk * 8 + 6]), "v"(s[kt][kk * 8 + 7]));
        asm("v_permlane32_swap_b32 %0, %1" : "+v"(a0), "+v"(b0));
        asm("v_permlane32_swap_b32 %0, %1" : "+v"(a1), "+v"(b1));
        union { unsigned u[4]; short8 v; } pb;
        pb.u[0] = a0; pb.u[1] = a1; pb.u[2] = b0; pb.u[3] = b1;
#pragma unroll
        for (int dt = 0; dt < 2; dt++) {
          short8 vf = *(const short8*)(&vS[(dt * 32 + l31) * KV_S + kt * 32 + kk * 16 + hi * 8]);
          oacc[dt] = __builtin_amdgcn_mfma_f32_32x32x16_bf16(vf, pb.v, oacc[dt], 0, 0, 0);
        }
      }
    }
  }

  float inv = 1.0f / lsum;
  float* orow = out + ((size_t)b * 4096 + qb0 + l31) * 768 + h * 64;
#pragma unroll
  for (int dt = 0; dt < 2; dt++)
#pragma unroll
    for (int g = 0; g < 4; g++) {
      float4 o;
      o.x = oacc[dt][g * 4 + 0] * inv;
      o.y = oacc[dt][g * 4 + 1] * inv;
      o.z = oacc[dt][g * 4 + 2] * inv;
      o.w = oacc[dt][g * 4 + 3] * inv;
      *(float4*)(orow + dt * 32 + g * 8 + hi * 4) = o;
    }
}

extern "C" void kernel_launch(void* const* d_in, const int* in_sizes, int n_in,
                              void* d_out, int out_size, void* d_ws, size_t ws_size,
                              hipStream_t stream) {
  const float* x = (const float*)d_in[0];      // 4 x 4096 x 768
  const float* w = (const float*)d_in[1];      // 768 x 2304
  const float* bias = (const float*)d_in[2];   // 2304
  float* out = (float*)d_out;                  // 4 x 4096 x 768 fp32

  char* ws = (char*)d_ws;
  unsigned short* xb = (unsigned short*)ws;                       // 16384x768 bf16
  unsigned short* wt = (unsigned short*)(ws + 25165824);          // 2304x768 bf16
  unsigned short* Qb = (unsigned short*)(ws + 25165824 + 3538944);
  unsigned short* Kb = Qb + 12582912;
  unsigned short* Vb = Kb + 12582912;

  hipLaunchKernelGGL(cast_x_kernel, dim3(12288), dim3(256), 0, stream, x, xb, 3145728);
  hipLaunchKernelGGL(transpose_w_kernel, dim3(72, 24), dim3(32, 8), 0, stream, w, wt);
  hipLaunchKernelGGL(qkv_gemm_kernel, dim3(2304), dim3(256), 0, stream, xb, wt, bias, Qb, Kb, Vb);
  hipLaunchKernelGGL(rope_kernel, dim3(1536), dim3(256), 0, stream, Qb, Kb);
  hipLaunchKernelGGL(attn_kernel, dim3(32, 48), dim3(256), 0, stream, Qb, Kb, Vb, out);
}